// Round 17
// baseline (221.850 us; speedup 1.0000x reference)
//
#include <hip/hip_runtime.h>
#include <hip/hip_bf16.h>
#include <cstdint>

#define NTOT 73728      // B*H*W = 32*48*48
#define CTOT 512
#define MGRP 128        // members per group
#define EPSV 1e-7f

typedef float4 f4;
typedef __attribute__((ext_vector_type(8))) short bf16x8;   // 8 bf16 (4 VGPRs)
typedef __attribute__((ext_vector_type(4))) float f32x4;
typedef __attribute__((ext_vector_type(16))) float f32x16;

__device__ __forceinline__ f4 ld4(const float* p){ return *(const f4*)p; }

__device__ __forceinline__ uint32_t pk2(float a, float b){   // HW v_cvt_pk_bf16_f32
    __hip_bfloat162 h = __float22bfloat162_rn(make_float2(a, b));
    uint32_t u; __builtin_memcpy(&u, &h, 4);
    return u;
}

__device__ __forceinline__ bf16x8 pack8(const float v[8]) {
    union { bf16x8 b; uint32_t u[4]; } r;
#pragma unroll
    for (int i = 0; i < 4; ++i) r.u[i] = pk2(v[2*i], v[2*i+1]);
    return r.b;
}

// ---------------- K1: Sxx partials — 32-sample K-tiles, 4 blocks/CU ----------------
// grid (nchunk=256, 4), block 256 (4 waves 2x2; wave tile 64x64 of 128x128).
// LDS fp32 [32][128] (16 KB) x2 dbuf, 1 barrier/tile. Staging: 4 coalesced ld4/thread
// with 1-tile register prefetch. rowsPer = 288 (9 tiles).
__global__ __launch_bounds__(256) void k_cov(
    const float* __restrict__ x, float* __restrict__ sxxPart,
    float* __restrict__ sxPart, int nchunk, int rowsPer)
{
    const int chunk = blockIdx.x, g = blockIdx.y;
    const int t = threadIdx.x;
    const int lane = t & 63, wid = t >> 6;
    const int wr = wid >> 1, wc = wid & 1;
    const int l31 = lane & 31, hi = lane >> 5;
    const size_t rowbase = (size_t)chunk * rowsPer;

    __shared__ float xs[2][32][128];   // 2 x 16 KB
    __shared__ float sxred[256];

    const int ssmp = t >> 5;           // staging sample 0..7 (+8,+16,+24)
    const int schk = t & 31;           // staging chunk (4 floats)
    const float* xp = x + (size_t)g * MGRP + (size_t)schk * 4;

    f32x16 acc[2][2];
#pragma unroll
    for (int a = 0; a < 2; ++a)
#pragma unroll
        for (int b = 0; b < 2; ++b) acc[a][b] = (f32x16){};
    float sxa0 = 0.f, sxa1 = 0.f;

    const int niter = rowsPer / 32;
    f4 r0 = ld4(xp + (rowbase + ssmp) * CTOT);
    f4 r1 = ld4(xp + (rowbase + 8 + ssmp) * CTOT);
    f4 r2 = ld4(xp + (rowbase + 16 + ssmp) * CTOT);
    f4 r3 = ld4(xp + (rowbase + 24 + ssmp) * CTOT);

    for (int it = 0; it < niter; ++it) {
        const int cur = it & 1;
        *(f32x4*)&xs[cur][ssmp][schk * 4]      = (f32x4){r0.x, r0.y, r0.z, r0.w};
        *(f32x4*)&xs[cur][8 + ssmp][schk * 4]  = (f32x4){r1.x, r1.y, r1.z, r1.w};
        *(f32x4*)&xs[cur][16 + ssmp][schk * 4] = (f32x4){r2.x, r2.y, r2.z, r2.w};
        *(f32x4*)&xs[cur][24 + ssmp][schk * 4] = (f32x4){r3.x, r3.y, r3.z, r3.w};
        __syncthreads();                 // single barrier/tile (dbuf)
        if (it + 1 < niter) {            // prefetch next tile (in flight under compute)
            const float* np = xp + (rowbase + (size_t)(it + 1) * 32) * CTOT;
            r0 = ld4(np + (size_t)ssmp * CTOT);
            r1 = ld4(np + (size_t)(8 + ssmp) * CTOT);
            r2 = ld4(np + (size_t)(16 + ssmp) * CTOT);
            r3 = ld4(np + (size_t)(24 + ssmp) * CTOT);
        }
#pragma unroll
        for (int ks = 0; ks < 2; ++ks) {         // two 16-sample k-slices
            bf16x8 fa[2], fb[2];
#pragma unroll
            for (int a = 0; a < 2; ++a) {
                float v[8];
                const int ch = wr * 64 + a * 32 + l31;
#pragma unroll
                for (int e = 0; e < 8; ++e) v[e] = xs[cur][ks * 16 + hi * 8 + e][ch];
                if (wc == 0) {
                    float s = 0.f;
#pragma unroll
                    for (int e = 0; e < 8; ++e) s += v[e];
                    if (a == 0) sxa0 += s; else sxa1 += s;
                }
                fa[a] = pack8(v);
            }
            if (wr != wc) {
#pragma unroll
                for (int b = 0; b < 2; ++b) {
                    float v[8];
                    const int ch = wc * 64 + b * 32 + l31;
#pragma unroll
                    for (int e = 0; e < 8; ++e) v[e] = xs[cur][ks * 16 + hi * 8 + e][ch];
                    fb[b] = pack8(v);
                }
            } else {
                fb[0] = fa[0]; fb[1] = fa[1];
            }
#pragma unroll
            for (int a = 0; a < 2; ++a)
#pragma unroll
                for (int b = 0; b < 2; ++b)
                    acc[a][b] = __builtin_amdgcn_mfma_f32_32x32x16_bf16(
                        fa[a], fb[b], acc[a][b], 0, 0, 0);
        }
    }

    float* op = sxxPart + ((size_t)g * nchunk + chunk) * 16384;
#pragma unroll
    for (int a = 0; a < 2; ++a)
#pragma unroll
        for (int b = 0; b < 2; ++b)
#pragma unroll
            for (int r = 0; r < 16; ++r) {
                int i = wr*64 + a*32 + (r & 3) + 8 * (r >> 2) + 4 * hi;
                int j = wc*64 + b*32 + l31;
                op[i * 128 + j] = acc[a][b][r];
            }

    if (wc == 0) {
        sxred[(wr*64 + l31) * 2 + hi]      = sxa0;
        sxred[(wr*64 + 32 + l31) * 2 + hi] = sxa1;
    }
    __syncthreads();
    if (t < 128)
        sxPart[((size_t)g * nchunk + chunk) * 128 + t] = sxred[t*2] + sxred[t*2 + 1];
}

// ---------------- K2: reduce Sxx partials over chunks ----------------
__global__ __launch_bounds__(256) void k_reduce(
    const float* __restrict__ sxxPart, float* __restrict__ gSxx, int nchunk)
{
    int g = blockIdx.y;
    int idx = blockIdx.x * 256 + threadIdx.x;
    float s = 0.f;
#pragma unroll 8
    for (int c = 0; c < nchunk; ++c)
        s += sxxPart[((size_t)g * nchunk + c) * 16384 + idx];
    gSxx[g * 16384 + idx] = s;
}

// ---------------- K3: finalize -> mean, trace, sigma, P1 ----------------
__global__ __launch_bounds__(256) void k_finalize(
    const float* __restrict__ gSxx, const float* __restrict__ sxPart,
    float* __restrict__ gSigma, float* __restrict__ gP,
    float* __restrict__ gMean, float* __restrict__ gScale, int nchunk)
{
    int g = blockIdx.x, t = threadIdx.x;
    __shared__ float mu[128];
    __shared__ float red[256];

    if (t < 128) {
        float s = 0.f;
        for (int c = 0; c < nchunk; ++c)
            s += sxPart[((size_t)g * nchunk + c) * 128 + t];
        float m = s / (float)NTOT;
        mu[t] = m;
        gMean[g * 128 + t] = m;
    }
    __syncthreads();

    float d = 0.f;
    if (t < 128) {
        float vdiag = gSxx[g * 16384 + t * 128 + t];
        float cv = (vdiag - (float)NTOT * mu[t] * mu[t]) / ((float)NTOT - 1.f);
        d = (1.f - EPSV) * cv + EPSV;
    }
    red[t] = d;
    __syncthreads();
    for (int s = 128; s > 0; s >>= 1) {
        if (t < s) red[t] += red[t + s];
        __syncthreads();
    }
    float tr = red[0];
    float invTr = 1.f / tr;
    if (t == 0) gScale[g] = rsqrtf(tr);

    for (int e = t; e < 16384; e += 256) {
        int i = e >> 7, j = e & 127;
        float cv = (gSxx[g * 16384 + e] - (float)NTOT * mu[i] * mu[j]) / ((float)NTOT - 1.f);
        float ce = (1.f - EPSV) * cv + ((i == j) ? EPSV : 0.f);
        float sg = ce * invTr;
        gSigma[g * 16384 + e] = sg;
        gP[g * 16384 + e] = ((i == j) ? 1.5f : 0.f) - 0.5f * sg;
    }
}

// ---------------- K4: P2 = P@P, PS = P@Sigma ----------------
__global__ __launch_bounds__(256) void k_ns1(
    const float* __restrict__ gP, const float* __restrict__ gS,
    float* __restrict__ gP2, float* __restrict__ gPS)
{
    int g = blockIdx.y;
    int row = blockIdx.x * 8 + (threadIdx.x >> 5);
    int cq = (threadIdx.x & 31) * 4;
    const float* P = gP + g * 16384;
    const float* S = gS + g * 16384;
    f4 a1 = {0.f,0.f,0.f,0.f}, a2 = {0.f,0.f,0.f,0.f};
    for (int k = 0; k < 128; k += 4) {
        f4 a = ld4(&P[row * 128 + k]);
        float av[4] = {a.x, a.y, a.z, a.w};
#pragma unroll
        for (int kk = 0; kk < 4; ++kk) {
            f4 b1 = ld4(&P[(k + kk) * 128 + cq]);
            f4 b2 = ld4(&S[(k + kk) * 128 + cq]);
            float aa = av[kk];
            a1.x += aa * b1.x; a1.y += aa * b1.y; a1.z += aa * b1.z; a1.w += aa * b1.w;
            a2.x += aa * b2.x; a2.y += aa * b2.y; a2.z += aa * b2.z; a2.w += aa * b2.w;
        }
    }
    *(f4*)&gP2[g * 16384 + row * 128 + cq] = a1;
    *(f4*)&gPS[g * 16384 + row * 128 + cq] = a2;
}

// ---------------- K5: P = 1.5P - 0.5*(P2@PS); final iter emits W'' = diag(sc*gamma)@W ----
__global__ __launch_bounds__(256) void k_ns2(
    float* __restrict__ gP, const float* __restrict__ gP2, const float* __restrict__ gPS,
    const float* __restrict__ gScale, const float* __restrict__ gamma,
    ushort* __restrict__ gWb, int writeW)
{
    int g = blockIdx.y;
    int row = blockIdx.x * 8 + (threadIdx.x >> 5);
    int cq = (threadIdx.x & 31) * 4;
    const float* A = gP2 + g * 16384;
    const float* B = gPS + g * 16384;
    f4 acc = {0.f,0.f,0.f,0.f};
    for (int k = 0; k < 128; k += 4) {
        f4 a = ld4(&A[row * 128 + k]);
        float av[4] = {a.x, a.y, a.z, a.w};
#pragma unroll
        for (int kk = 0; kk < 4; ++kk) {
            f4 b = ld4(&B[(k + kk) * 128 + cq]);
            float aa = av[kk];
            acc.x += aa * b.x; acc.y += aa * b.y; acc.z += aa * b.z; acc.w += aa * b.w;
        }
    }
    size_t off = (size_t)g * 16384 + row * 128 + cq;
    f4 p = ld4(&gP[off]);
    f4 r;
    r.x = 1.5f * p.x - 0.5f * acc.x;
    r.y = 1.5f * p.y - 0.5f * acc.y;
    r.z = 1.5f * p.z - 0.5f * acc.z;
    r.w = 1.5f * p.w - 0.5f * acc.w;
    *(f4*)&gP[off] = r;
    if (writeW) {
        float sg = gScale[g] * gamma[g * 128 + row];
        uint32_t lo = pk2(r.x * sg, r.y * sg);
        uint32_t h2 = pk2(r.z * sg, r.w * sg);
        *(uint2*)&gWb[off] = make_uint2(lo, h2);
    }
}

// ---------------- K6: beta' = beta - gamma*(W@mu) ----------------
__global__ __launch_bounds__(128) void k_bprime(
    const float* __restrict__ gP, const float* __restrict__ gMean,
    const float* __restrict__ gScale, const float* __restrict__ gamma,
    const float* __restrict__ beta, float* __restrict__ gBp)
{
    int g = blockIdx.x, j = threadIdx.x;
    float s = 0.f;
    for (int k = 0; k < 128; ++k)
        s += gMean[g * 128 + k] * gP[g * 16384 + k * 128 + j];
    s *= gScale[g];
    int c = g * 128 + j;
    gBp[c] = beta[c] - gamma[c] * s;
}

// ---------------- K7: out = (bf16(X) @ W'') + beta'  (gamma folded into W'') ----------
// grid (288, 4), block 256 (4 waves). Each wave: 2 consecutive 32-sample tiles,
// 1-deep register prefetch of A; W'' staged once in LDS (XOR-swizzled 16B slots).
__global__ __launch_bounds__(256) void k_apply(
    const float* __restrict__ x, const ushort* __restrict__ gWb,
    const float* __restrict__ gBp, float* __restrict__ out)
{
    const int g = blockIdx.y;
    const int t = threadIdx.x, lane = t & 63, w = t >> 6;
    const int l31 = lane & 31, hi = lane >> 5;

    __shared__ ushort Wl[16384];   // 32 KB, rows of 256B = 16 slots of 16B

    // stage W'' (all 2048 x 16B): logical slot s of row -> physical slot s^(row&15)
    {
        const uint4* src = (const uint4*)(gWb + (size_t)g * 16384);
#pragma unroll
        for (int q = 0; q < 8; ++q) {
            int i = q * 256 + t;          // 0..2047
            int row = i >> 4, s = i & 15;
            uint4 v = src[i];
            *(uint4*)&Wl[row * 128 + ((s ^ (row & 15)) * 8)] = v;
        }
    }
    __syncthreads();

    float bp[4];
#pragma unroll
    for (int ct = 0; ct < 4; ++ct)
        bp[ct] = gBp[g * MGRP + ct * 32 + l31];

    const int base = (blockIdx.x * 4 + w) * 64;
    const float* ap = x + (size_t)(base + l31) * CTOT + g * MGRP + hi * 8;

    f4 st0[8], st1[8];
#pragma unroll
    for (int ks = 0; ks < 8; ++ks) {
        st0[ks] = ld4(ap + ks * 16);
        st1[ks] = ld4(ap + ks * 16 + 4);
    }

#pragma unroll
    for (int tile = 0; tile < 2; ++tile) {
        bf16x8 af[8];
#pragma unroll
        for (int ks = 0; ks < 8; ++ks) {
            union { bf16x8 b; uint32_t u[4]; } cv;
            cv.u[0] = pk2(st0[ks].x, st0[ks].y);
            cv.u[1] = pk2(st0[ks].z, st0[ks].w);
            cv.u[2] = pk2(st1[ks].x, st1[ks].y);
            cv.u[3] = pk2(st1[ks].z, st1[ks].w);
            af[ks] = cv.b;
        }
        if (tile < 1) {   // prefetch second tile's A while computing first
            const float* np = ap + (size_t)32 * CTOT;
#pragma unroll
            for (int ks = 0; ks < 8; ++ks) {
                st0[ks] = ld4(np + ks * 16);
                st1[ks] = ld4(np + ks * 16 + 4);
            }
        }
        const int s0 = base + tile * 32;
#pragma unroll
        for (int ct = 0; ct < 4; ++ct) {
            const int row = ct * 32 + l31;
            f32x16 acc = {};
#pragma unroll
            for (int ks = 0; ks < 8; ++ks) {
                int slot = (ks * 2 + hi) ^ (row & 15);
                bf16x8 wf = *(const bf16x8*)&Wl[row * 128 + slot * 8];
                acc = __builtin_amdgcn_mfma_f32_32x32x16_bf16(af[ks], wf, acc, 0, 0, 0);
            }
#pragma unroll
            for (int r = 0; r < 16; ++r) {
                int orow = s0 + (r & 3) + 8 * (r >> 2) + 4 * hi;
                float val = acc[r] + bp[ct];
                __builtin_nontemporal_store(val,
                    &out[(size_t)orow * CTOT + g * MGRP + ct * 32 + l31]);
            }
        }
    }
}

// ---------------- launch ----------------
extern "C" void kernel_launch(void* const* d_in, const int* in_sizes, int n_in,
                              void* d_out, int out_size, void* d_ws, size_t ws_size,
                              hipStream_t stream)
{
    const float* x     = (const float*)d_in[0];
    const float* gamma = (const float*)d_in[1];
    const float* beta  = (const float*)d_in[2];
    float* out = (float*)d_out;
    float* ws  = (float*)d_ws;

    int nchunk = 256;   // rowsPer = 288 (divisible by 32); 1024 blocks = 4/CU
    auto need = [](int nc) -> size_t {
        return ((size_t)nc * 4 * 16384 + (size_t)nc * 4 * 128 +
                5ull * 4 * 16384 + 512 + 16 + 512 + 32768) * 4;
    };
    while (nchunk > 16 && need(nchunk) > ws_size) nchunk >>= 1;
    int rowsPer = NTOT / nchunk;

    size_t off = 0;
    float* sxxPart = ws + off; off += (size_t)nchunk * 4 * 16384;
    float* sxPart  = ws + off; off += (size_t)nchunk * 4 * 128;
    float* gSxx    = ws + off; off += 4 * 16384;
    float* gSigma  = ws + off; off += 4 * 16384;
    float* gP      = ws + off; off += 4 * 16384;
    float* gP2     = ws + off; off += 4 * 16384;
    float* gPS     = ws + off; off += 4 * 16384;
    float* gMean   = ws + off; off += 512;
    float* gScale  = ws + off; off += 16;
    float* gBp     = ws + off; off += 512;
    ushort* gWb    = (ushort*)(ws + off); off += 32768;   // 4*16384 bf16 = 32768 float-slots

    k_cov<<<dim3(nchunk, 4), 256, 0, stream>>>(x, sxxPart, sxPart, nchunk, rowsPer);
    k_reduce<<<dim3(64, 4), 256, 0, stream>>>(sxxPart, gSxx, nchunk);
    k_finalize<<<4, 256, 0, stream>>>(gSxx, sxPart, gSigma, gP, gMean, gScale, nchunk);
    k_ns1<<<dim3(16, 4), 256, 0, stream>>>(gP, gSigma, gP2, gPS);
    k_ns2<<<dim3(16, 4), 256, 0, stream>>>(gP, gP2, gPS, gScale, gamma, gWb, 0);
    k_ns1<<<dim3(16, 4), 256, 0, stream>>>(gP, gSigma, gP2, gPS);
    k_ns2<<<dim3(16, 4), 256, 0, stream>>>(gP, gP2, gPS, gScale, gamma, gWb, 1);
    k_bprime<<<4, 128, 0, stream>>>(gP, gMean, gScale, gamma, beta, gBp);
    k_apply<<<dim3(288, 4), 256, 0, stream>>>(x, gWb, gBp, out);
}

// Round 18
// 175.283 us; speedup vs baseline: 1.2657x; 1.2657x over previous
//
#include <hip/hip_runtime.h>
#include <hip/hip_bf16.h>
#include <cstdint>

#define NTOT 73728      // B*H*W = 32*48*48
#define CTOT 512
#define MGRP 128        // members per group
#define EPSV 1e-7f

typedef float4 f4;
typedef __attribute__((ext_vector_type(8))) short bf16x8;   // 8 bf16 (4 VGPRs)
typedef __attribute__((ext_vector_type(4))) float f32x4;
typedef __attribute__((ext_vector_type(16))) float f32x16;

__device__ __forceinline__ f4 ld4(const float* p){ return *(const f4*)p; }

__device__ __forceinline__ uint32_t pk2(float a, float b){   // HW v_cvt_pk_bf16_f32
    __hip_bfloat162 h = __float22bfloat162_rn(make_float2(a, b));
    uint32_t u; __builtin_memcpy(&u, &h, 4);
    return u;
}

__device__ __forceinline__ bf16x8 pack8(const float v[8]) {
    union { bf16x8 b; uint32_t u[4]; } r;
#pragma unroll
    for (int i = 0; i < 4; ++i) r.u[i] = pk2(v[2*i], v[2*i+1]);
    return r.b;
}

// ---------------- K1: Sxx partials — k-quad-interleaved LDS, b128 frag reads ----------
// grid (nchunk=128, 4), block 256 (4 waves 2x2; wave tile 64x64 of 128x128).
// LDS layout: addr_dw(k,ch) = (k>>2)*512 + sigma(ch)*4 + (k&3), sigma = (ch>>2)+(ch&3)*32.
//   write (per thread, 4 consecutive samples x 4 ch): 4 x b128, banks 4*schk -> even.
//   frag read (8 k for fixed ch): 2 x b128, banks 4*(l31>>2) -> even.  Both at LDS floor.
__global__ __launch_bounds__(256) void k_cov(
    const float* __restrict__ x, float* __restrict__ sxxPart,
    float* __restrict__ sxPart, int nchunk, int rowsPer)
{
    const int chunk = blockIdx.x, g = blockIdx.y;
    const int t = threadIdx.x;
    const int lane = t & 63, wid = t >> 6;
    const int wr = wid >> 1, wc = wid & 1;
    const int l31 = lane & 31, hi = lane >> 5;
    const size_t rowbase = (size_t)chunk * rowsPer;

    __shared__ float xs[2][4096];   // 2 x 16 KB
    __shared__ float sxred[256];

    const int kq0  = t >> 5;           // k-quad 0..7 (samples 4*kq0 .. 4*kq0+3)
    const int schk = t & 31;           // channel quad
    const float* xp = x + (size_t)g * MGRP + (size_t)schk * 4;
    const int wbase = kq0 * 512 + schk * 4;

    f32x16 acc[2][2];
#pragma unroll
    for (int a = 0; a < 2; ++a)
#pragma unroll
        for (int b = 0; b < 2; ++b) acc[a][b] = (f32x16){};
    float sxa0 = 0.f, sxa1 = 0.f;

    const int niter = rowsPer / 32;
    f4 r0 = ld4(xp + (rowbase + kq0*4 + 0) * CTOT);
    f4 r1 = ld4(xp + (rowbase + kq0*4 + 1) * CTOT);
    f4 r2 = ld4(xp + (rowbase + kq0*4 + 2) * CTOT);
    f4 r3 = ld4(xp + (rowbase + kq0*4 + 3) * CTOT);

    for (int it = 0; it < niter; ++it) {
        const int cur = it & 1;
        // transpose-in-registers: channel j across the 4 k's -> one b128 each
        *(f32x4*)&xs[cur][wbase +   0] = (f32x4){r0.x, r1.x, r2.x, r3.x};
        *(f32x4*)&xs[cur][wbase + 128] = (f32x4){r0.y, r1.y, r2.y, r3.y};
        *(f32x4*)&xs[cur][wbase + 256] = (f32x4){r0.z, r1.z, r2.z, r3.z};
        *(f32x4*)&xs[cur][wbase + 384] = (f32x4){r0.w, r1.w, r2.w, r3.w};
        __syncthreads();                 // single barrier/tile (dbuf)
        if (it + 1 < niter) {            // prefetch next tile
            const float* np = xp + (rowbase + (size_t)(it + 1) * 32 + kq0*4) * CTOT;
            r0 = ld4(np);
            r1 = ld4(np + CTOT);
            r2 = ld4(np + 2 * CTOT);
            r3 = ld4(np + 3 * CTOT);
        }
#pragma unroll
        for (int ks = 0; ks < 2; ++ks) {         // two 16-sample k-slices
            const int rbase = (ks*4 + hi*2) * 512 + (l31 >> 2) * 4 + (l31 & 3) * 128;
            bf16x8 fa[2], fb[2];
#pragma unroll
            for (int a = 0; a < 2; ++a) {
                const int ra = rbase + (wr*16 + a*8) * 4;
                f32x4 lo = *(const f32x4*)&xs[cur][ra];
                f32x4 hi4 = *(const f32x4*)&xs[cur][ra + 512];
                float v[8] = {lo.x, lo.y, lo.z, lo.w, hi4.x, hi4.y, hi4.z, hi4.w};
                if (wc == 0) {
                    float s = v[0]+v[1]+v[2]+v[3]+v[4]+v[5]+v[6]+v[7];
                    if (a == 0) sxa0 += s; else sxa1 += s;
                }
                fa[a] = pack8(v);
            }
            if (wr != wc) {
#pragma unroll
                for (int b = 0; b < 2; ++b) {
                    const int rb = rbase + (wc*16 + b*8) * 4;
                    f32x4 lo = *(const f32x4*)&xs[cur][rb];
                    f32x4 hi4 = *(const f32x4*)&xs[cur][rb + 512];
                    float v[8] = {lo.x, lo.y, lo.z, lo.w, hi4.x, hi4.y, hi4.z, hi4.w};
                    fb[b] = pack8(v);
                }
            } else {
                fb[0] = fa[0]; fb[1] = fa[1];
            }
#pragma unroll
            for (int a = 0; a < 2; ++a)
#pragma unroll
                for (int b = 0; b < 2; ++b)
                    acc[a][b] = __builtin_amdgcn_mfma_f32_32x32x16_bf16(
                        fa[a], fb[b], acc[a][b], 0, 0, 0);
        }
    }

    float* op = sxxPart + ((size_t)g * nchunk + chunk) * 16384;
#pragma unroll
    for (int a = 0; a < 2; ++a)
#pragma unroll
        for (int b = 0; b < 2; ++b)
#pragma unroll
            for (int r = 0; r < 16; ++r) {
                int i = wr*64 + a*32 + (r & 3) + 8 * (r >> 2) + 4 * hi;
                int j = wc*64 + b*32 + l31;
                op[i * 128 + j] = acc[a][b][r];
            }

    if (wc == 0) {
        sxred[(wr*64 + l31) * 2 + hi]      = sxa0;
        sxred[(wr*64 + 32 + l31) * 2 + hi] = sxa1;
    }
    __syncthreads();
    if (t < 128)
        sxPart[((size_t)g * nchunk + chunk) * 128 + t] = sxred[t*2] + sxred[t*2 + 1];
}

// ---------------- K2: reduce Sxx partials over chunks ----------------
__global__ __launch_bounds__(256) void k_reduce(
    const float* __restrict__ sxxPart, float* __restrict__ gSxx, int nchunk)
{
    int g = blockIdx.y;
    int idx = blockIdx.x * 256 + threadIdx.x;
    float s = 0.f;
#pragma unroll 8
    for (int c = 0; c < nchunk; ++c)
        s += sxxPart[((size_t)g * nchunk + c) * 16384 + idx];
    gSxx[g * 16384 + idx] = s;
}

// ---------------- K3: finalize -> mean, trace, sigma, P1 ----------------
__global__ __launch_bounds__(256) void k_finalize(
    const float* __restrict__ gSxx, const float* __restrict__ sxPart,
    float* __restrict__ gSigma, float* __restrict__ gP,
    float* __restrict__ gMean, float* __restrict__ gScale, int nchunk)
{
    int g = blockIdx.x, t = threadIdx.x;
    __shared__ float mu[128];
    __shared__ float red[256];

    if (t < 128) {
        float s = 0.f;
        for (int c = 0; c < nchunk; ++c)
            s += sxPart[((size_t)g * nchunk + c) * 128 + t];
        float m = s / (float)NTOT;
        mu[t] = m;
        gMean[g * 128 + t] = m;
    }
    __syncthreads();

    float d = 0.f;
    if (t < 128) {
        float vdiag = gSxx[g * 16384 + t * 128 + t];
        float cv = (vdiag - (float)NTOT * mu[t] * mu[t]) / ((float)NTOT - 1.f);
        d = (1.f - EPSV) * cv + EPSV;
    }
    red[t] = d;
    __syncthreads();
    for (int s = 128; s > 0; s >>= 1) {
        if (t < s) red[t] += red[t + s];
        __syncthreads();
    }
    float tr = red[0];
    float invTr = 1.f / tr;
    if (t == 0) gScale[g] = rsqrtf(tr);

    for (int e = t; e < 16384; e += 256) {
        int i = e >> 7, j = e & 127;
        float cv = (gSxx[g * 16384 + e] - (float)NTOT * mu[i] * mu[j]) / ((float)NTOT - 1.f);
        float ce = (1.f - EPSV) * cv + ((i == j) ? EPSV : 0.f);
        float sg = ce * invTr;
        gSigma[g * 16384 + e] = sg;
        gP[g * 16384 + e] = ((i == j) ? 1.5f : 0.f) - 0.5f * sg;
    }
}

// ---------------- K4: P2 = P@P, PS = P@Sigma ----------------
__global__ __launch_bounds__(256) void k_ns1(
    const float* __restrict__ gP, const float* __restrict__ gS,
    float* __restrict__ gP2, float* __restrict__ gPS)
{
    int g = blockIdx.y;
    int row = blockIdx.x * 8 + (threadIdx.x >> 5);
    int cq = (threadIdx.x & 31) * 4;
    const float* P = gP + g * 16384;
    const float* S = gS + g * 16384;
    f4 a1 = {0.f,0.f,0.f,0.f}, a2 = {0.f,0.f,0.f,0.f};
    for (int k = 0; k < 128; k += 4) {
        f4 a = ld4(&P[row * 128 + k]);
        float av[4] = {a.x, a.y, a.z, a.w};
#pragma unroll
        for (int kk = 0; kk < 4; ++kk) {
            f4 b1 = ld4(&P[(k + kk) * 128 + cq]);
            f4 b2 = ld4(&S[(k + kk) * 128 + cq]);
            float aa = av[kk];
            a1.x += aa * b1.x; a1.y += aa * b1.y; a1.z += aa * b1.z; a1.w += aa * b1.w;
            a2.x += aa * b2.x; a2.y += aa * b2.y; a2.z += aa * b2.z; a2.w += aa * b2.w;
        }
    }
    *(f4*)&gP2[g * 16384 + row * 128 + cq] = a1;
    *(f4*)&gPS[g * 16384 + row * 128 + cq] = a2;
}

// ---------------- K5: P = 1.5P - 0.5*(P2@PS); final iter emits W'' = diag(sc*gamma)@W ----
__global__ __launch_bounds__(256) void k_ns2(
    float* __restrict__ gP, const float* __restrict__ gP2, const float* __restrict__ gPS,
    const float* __restrict__ gScale, const float* __restrict__ gamma,
    ushort* __restrict__ gWb, int writeW)
{
    int g = blockIdx.y;
    int row = blockIdx.x * 8 + (threadIdx.x >> 5);
    int cq = (threadIdx.x & 31) * 4;
    const float* A = gP2 + g * 16384;
    const float* B = gPS + g * 16384;
    f4 acc = {0.f,0.f,0.f,0.f};
    for (int k = 0; k < 128; k += 4) {
        f4 a = ld4(&A[row * 128 + k]);
        float av[4] = {a.x, a.y, a.z, a.w};
#pragma unroll
        for (int kk = 0; kk < 4; ++kk) {
            f4 b = ld4(&B[(k + kk) * 128 + cq]);
            float aa = av[kk];
            acc.x += aa * b.x; acc.y += aa * b.y; acc.z += aa * b.z; acc.w += aa * b.w;
        }
    }
    size_t off = (size_t)g * 16384 + row * 128 + cq;
    f4 p = ld4(&gP[off]);
    f4 r;
    r.x = 1.5f * p.x - 0.5f * acc.x;
    r.y = 1.5f * p.y - 0.5f * acc.y;
    r.z = 1.5f * p.z - 0.5f * acc.z;
    r.w = 1.5f * p.w - 0.5f * acc.w;
    *(f4*)&gP[off] = r;
    if (writeW) {
        float sg = gScale[g] * gamma[g * 128 + row];
        uint32_t lo = pk2(r.x * sg, r.y * sg);
        uint32_t h2 = pk2(r.z * sg, r.w * sg);
        *(uint2*)&gWb[off] = make_uint2(lo, h2);
    }
}

// ---------------- K6: beta' = beta - gamma*(W@mu) ----------------
__global__ __launch_bounds__(128) void k_bprime(
    const float* __restrict__ gP, const float* __restrict__ gMean,
    const float* __restrict__ gScale, const float* __restrict__ gamma,
    const float* __restrict__ beta, float* __restrict__ gBp)
{
    int g = blockIdx.x, j = threadIdx.x;
    float s = 0.f;
    for (int k = 0; k < 128; ++k)
        s += gMean[g * 128 + k] * gP[g * 16384 + k * 128 + j];
    s *= gScale[g];
    int c = g * 128 + j;
    gBp[c] = beta[c] - gamma[c] * s;
}

// ---------------- K7: out = (bf16(X) @ W'') + beta'  (gamma folded into W'') ----------
// grid (288, 4), block 256 (4 waves). Each wave: 2 consecutive 32-sample tiles,
// 1-deep register prefetch of A; W'' staged once in LDS (XOR-swizzled 16B slots).
__global__ __launch_bounds__(256) void k_apply(
    const float* __restrict__ x, const ushort* __restrict__ gWb,
    const float* __restrict__ gBp, float* __restrict__ out)
{
    const int g = blockIdx.y;
    const int t = threadIdx.x, lane = t & 63, w = t >> 6;
    const int l31 = lane & 31, hi = lane >> 5;

    __shared__ ushort Wl[16384];   // 32 KB, rows of 256B = 16 slots of 16B

    // stage W'' (all 2048 x 16B): logical slot s of row -> physical slot s^(row&15)
    {
        const uint4* src = (const uint4*)(gWb + (size_t)g * 16384);
#pragma unroll
        for (int q = 0; q < 8; ++q) {
            int i = q * 256 + t;          // 0..2047
            int row = i >> 4, s = i & 15;
            uint4 v = src[i];
            *(uint4*)&Wl[row * 128 + ((s ^ (row & 15)) * 8)] = v;
        }
    }
    __syncthreads();

    float bp[4];
#pragma unroll
    for (int ct = 0; ct < 4; ++ct)
        bp[ct] = gBp[g * MGRP + ct * 32 + l31];

    const int base = (blockIdx.x * 4 + w) * 64;
    const float* ap = x + (size_t)(base + l31) * CTOT + g * MGRP + hi * 8;

    f4 st0[8], st1[8];
#pragma unroll
    for (int ks = 0; ks < 8; ++ks) {
        st0[ks] = ld4(ap + ks * 16);
        st1[ks] = ld4(ap + ks * 16 + 4);
    }

#pragma unroll
    for (int tile = 0; tile < 2; ++tile) {
        bf16x8 af[8];
#pragma unroll
        for (int ks = 0; ks < 8; ++ks) {
            union { bf16x8 b; uint32_t u[4]; } cv;
            cv.u[0] = pk2(st0[ks].x, st0[ks].y);
            cv.u[1] = pk2(st0[ks].z, st0[ks].w);
            cv.u[2] = pk2(st1[ks].x, st1[ks].y);
            cv.u[3] = pk2(st1[ks].z, st1[ks].w);
            af[ks] = cv.b;
        }
        if (tile < 1) {   // prefetch second tile's A while computing first
            const float* np = ap + (size_t)32 * CTOT;
#pragma unroll
            for (int ks = 0; ks < 8; ++ks) {
                st0[ks] = ld4(np + ks * 16);
                st1[ks] = ld4(np + ks * 16 + 4);
            }
        }
        const int s0 = base + tile * 32;
#pragma unroll
        for (int ct = 0; ct < 4; ++ct) {
            const int row = ct * 32 + l31;
            f32x16 acc = {};
#pragma unroll
            for (int ks = 0; ks < 8; ++ks) {
                int slot = (ks * 2 + hi) ^ (row & 15);
                bf16x8 wf = *(const bf16x8*)&Wl[row * 128 + slot * 8];
                acc = __builtin_amdgcn_mfma_f32_32x32x16_bf16(af[ks], wf, acc, 0, 0, 0);
            }
#pragma unroll
            for (int r = 0; r < 16; ++r) {
                int orow = s0 + (r & 3) + 8 * (r >> 2) + 4 * hi;
                float val = acc[r] + bp[ct];
                __builtin_nontemporal_store(val,
                    &out[(size_t)orow * CTOT + g * MGRP + ct * 32 + l31]);
            }
        }
    }
}

// ---------------- launch ----------------
extern "C" void kernel_launch(void* const* d_in, const int* in_sizes, int n_in,
                              void* d_out, int out_size, void* d_ws, size_t ws_size,
                              hipStream_t stream)
{
    const float* x     = (const float*)d_in[0];
    const float* gamma = (const float*)d_in[1];
    const float* beta  = (const float*)d_in[2];
    float* out = (float*)d_out;
    float* ws  = (float*)d_ws;

    int nchunk = 128;   // rowsPer = 576 (divisible by 32)
    auto need = [](int nc) -> size_t {
        return ((size_t)nc * 4 * 16384 + (size_t)nc * 4 * 128 +
                5ull * 4 * 16384 + 512 + 16 + 512 + 32768) * 4;
    };
    while (nchunk > 16 && need(nchunk) > ws_size) nchunk >>= 1;
    int rowsPer = NTOT / nchunk;

    size_t off = 0;
    float* sxxPart = ws + off; off += (size_t)nchunk * 4 * 16384;
    float* sxPart  = ws + off; off += (size_t)nchunk * 4 * 128;
    float* gSxx    = ws + off; off += 4 * 16384;
    float* gSigma  = ws + off; off += 4 * 16384;
    float* gP      = ws + off; off += 4 * 16384;
    float* gP2     = ws + off; off += 4 * 16384;
    float* gPS     = ws + off; off += 4 * 16384;
    float* gMean   = ws + off; off += 512;
    float* gScale  = ws + off; off += 16;
    float* gBp     = ws + off; off += 512;
    ushort* gWb    = (ushort*)(ws + off); off += 32768;   // 4*16384 bf16 = 32768 float-slots

    k_cov<<<dim3(nchunk, 4), 256, 0, stream>>>(x, sxxPart, sxPart, nchunk, rowsPer);
    k_reduce<<<dim3(64, 4), 256, 0, stream>>>(sxxPart, gSxx, nchunk);
    k_finalize<<<4, 256, 0, stream>>>(gSxx, sxPart, gSigma, gP, gMean, gScale, nchunk);
    k_ns1<<<dim3(16, 4), 256, 0, stream>>>(gP, gSigma, gP2, gPS);
    k_ns2<<<dim3(16, 4), 256, 0, stream>>>(gP, gP2, gPS, gScale, gamma, gWb, 0);
    k_ns1<<<dim3(16, 4), 256, 0, stream>>>(gP, gSigma, gP2, gPS);
    k_ns2<<<dim3(16, 4), 256, 0, stream>>>(gP, gP2, gPS, gScale, gamma, gWb, 1);
    k_bprime<<<4, 128, 0, stream>>>(gP, gMean, gScale, gamma, beta, gBp);
    k_apply<<<dim3(288, 4), 256, 0, stream>>>(x, gWb, gBp, out);
}